// Round 12
// baseline (63.629 us; speedup 1.0000x reference)
//
#include <hip/hip_runtime.h>

#define E_N 8192
#define V_N 2048
#define F_N 2048
#define B_N 8
#define H_N 128
#define DEC_N 128
#define EDGE_N 2
#define META_N 4
#define IN_DIM 134
#define MEMH 256
#define MEMAGG 128
#define AGGH 128

typedef __attribute__((ext_vector_type(8))) short short8;
typedef __attribute__((ext_vector_type(4))) float f32x4;
typedef __attribute__((ext_vector_type(4))) unsigned short ushort4v;

__device__ inline unsigned short f2bf(float x) {
    unsigned u = __float_as_uint(x);
    unsigned r = (u + 0x7FFFu + ((u >> 16) & 1u)) >> 16;
    return (unsigned short)r;
}

__device__ inline short8 pack8(float4 u0, float4 u1) {
    short8 s;
    s[0] = (short)f2bf(u0.x); s[1] = (short)f2bf(u0.y);
    s[2] = (short)f2bf(u0.z); s[3] = (short)f2bf(u0.w);
    s[4] = (short)f2bf(u1.x); s[5] = (short)f2bf(u1.y);
    s[6] = (short)f2bf(u1.z); s[7] = (short)f2bf(u1.w);
    return s;
}

// ---------------------------------------------------------------------------
// k_prep, ONE launch, latency-work FIRST / streaming-scan LAST:
//  [0,64)      FOLD W2A = W2 @ A1a -> direct MFMA B-frag bf16
//  64          b2A = b2 @ A1a (both branches)
//  [65,577)    zero NS* accumulators
//  [577,1025)  plain repack W1/A2 into MFMA B-frag bf16 (448 blocks)
//  [1025,5121) branch-free streaming one-hot scans (1 row/wave):
//              pos = sum (c+1)*m[c] - 1  (exact for one-hot f32 rows)
struct RDesc { const float* src; unsigned short* dst; int K; int N; int Kp; };
struct PrepArgs {
    const float* vmt; const float* fmt;
    int* vidx; int* fidx;
    const float* bvm; const int* active; const float* meta;
    float* emask; float* gfeat;
    float* nszero;
    const float* vM2w; const float* fM2w;
    const float* vA1w; const float* fA1w;
    const float* vM2b; const float* fM2b;
    unsigned short* w2afv;   // wpv + 40960 (256x128 frag)
    unsigned short* w2aff;   // wpf + 40960
    float* b2A;              // [0..127] var, [128..255] fun
    RDesc d[4];
};
__constant__ const int RP_CUM[5] = {0, 160, 224, 384, 448};

__global__ __launch_bounds__(256) void k_prep(PrepArgs P) {
    int bid = blockIdx.x, tid = threadIdx.x;
    if (bid >= 1025) {                      // streaming scan, 4096 blocks
        int row = (bid - 1025) * 4 + (tid >> 6);   // one row per wave
        int lane = tid & 63;
        bool isVar = row < E_N;
        const float* m = isVar ? P.vmt : P.fmt;
        int* out = isVar ? P.vidx : P.fidx;
        int e = isVar ? row : row - E_N;
        const float4* rp = (const float4*)(m + (size_t)e * V_N);
        float partial = 0.f;
#pragma unroll
        for (int j = 0; j < 8; ++j) {
            float4 v = rp[j * 64 + lane];
            float c = (float)((j * 64 + lane) * 4);
            partial += v.x * (c + 1.f) + v.y * (c + 2.f) +
                       v.z * (c + 3.f) + v.w * (c + 4.f);
        }
        unsigned long long bm = __ballot(partial != 0.f);
        int src = __ffsll((long long)bm) - 1;
        float total = __shfl(partial, src);
        int pos = (int)(total + 0.5f) - 1;
        if (lane == 0) {
            out[e] = pos;
            if (isVar) {
                const float4* bv = (const float4*)(P.bvm + pos * 8);
                float4 x0 = bv[0], x1 = bv[1];
                float s = x0.y + 2.f * x0.z + 3.f * x0.w +
                          4.f * x1.x + 5.f * x1.y + 6.f * x1.z + 7.f * x1.w;
                int b = (int)(s + 0.5f);
                P.emask[e] = (float)P.active[b];
                ((float4*)P.gfeat)[e] = ((const float4*)P.meta)[b];
            }
        }
        return;
    }
    if (bid < 64) {                         // W2A fold -> direct frag write
        int br = bid >> 5;
        const float* W2 = br ? P.fM2w : P.vM2w;
        const float* A1 = br ? P.fA1w : P.vA1w;
        unsigned short* dst = br ? P.w2aff : P.w2afv;
        int c  = tid & 127;
        int k0 = (bid & 31) * 8 + (tid >> 7) * 4;
        float acc0 = 0.f, acc1 = 0.f, acc2 = 0.f, acc3 = 0.f;
#pragma unroll 4
        for (int j = 0; j < 128; ++j) {
            float a1 = A1[(size_t)j * 128 + c];
            acc0 += W2[(size_t)(k0 + 0) * 128 + j] * a1;
            acc1 += W2[(size_t)(k0 + 1) * 128 + j] * a1;
            acc2 += W2[(size_t)(k0 + 2) * 128 + j] * a1;
            acc3 += W2[(size_t)(k0 + 3) * 128 + j] * a1;
        }
        int f    = (k0 >> 5) * 8 + (c >> 4);
        int lane = ((k0 >> 3) & 3) * 16 + (c & 15);
        ushort4v o;
        o[0] = f2bf(acc0); o[1] = f2bf(acc1); o[2] = f2bf(acc2); o[3] = f2bf(acc3);
        *(ushort4v*)(dst + ((size_t)(f * 64 + lane) * 8 + (k0 & 7))) = o;
        return;
    }
    if (bid == 64) {                        // b2A fold
        int n = tid & 127;
        const float* b2 = (tid < 128) ? P.vM2b : P.fM2b;
        const float* A1 = (tid < 128) ? P.vA1w : P.fA1w;
        float acc = 0.f;
#pragma unroll 8
        for (int j = 0; j < 128; ++j) acc += b2[j] * A1[(size_t)j * 128 + n];
        P.b2A[tid] = acc;
        return;
    }
    if (bid < 577) {                        // zero node sums: 512 blocks
        int gid = (bid - 65) * 256 + tid;
        ((float4*)P.nszero)[gid] = (float4){0.f, 0.f, 0.f, 0.f};
        return;
    }
    int rb = bid - 577;                     // plain repack: 448 blocks
    int mi = 0;
#pragma unroll
    for (int t = 1; t < 4; ++t) if (rb >= RP_CUM[t]) mi = t;
    RDesc d = P.d[mi];
    int i = (rb - RP_CUM[mi]) * 256 + tid;
    if (i >= d.Kp * d.N) return;
    int elem = i & 7;
    int lane = (i >> 3) & 63;
    int f    = i >> 9;
    int c16n = d.N >> 4;
    int c16 = f % c16n, kc = f / c16n;
    int k = kc * 32 + (lane >> 4) * 8 + elem;
    int c = c16 * 16 + (lane & 15);
    float v = (k < d.K) ? d.src[(size_t)k * d.N + c] : 0.f;
    d.dst[i] = f2bf(v);
}

// ---------------------------------------------------------------------------
// Fused MLP1 + folded-GEMM2: h1 = relu(dvs@W1+b1); Qb = h1@W2A + b2A
// -> global + atomic scatter into NS*. 16 edges/block (4 waves), grid 512x2.
struct F1Args {
    const float* dec[2];
    const float* ef;
    const float* gfeat;
    const unsigned short* wpack[2];  // W1f@0 (160x256), W2Af@40960 (256x128)
    const float* b1[2];
    const float* b2A[2];
    const int* idx[2];
    float* qb[2];
    float* ns[2];
};

__global__ __launch_bounds__(256, 6) void k_fused1(F1Args A) {
    int br = blockIdx.y;
    const float* dec = A.dec[br];
    const unsigned short* W1f = A.wpack[br];
    const unsigned short* W2f = A.wpack[br] + 160 * 256;
    const float* b1 = A.b1[br];
    const float* b2A = A.b2A[br];
    const int* idx = A.idx[br];
    float* qbo = A.qb[br];
    float* ns  = A.ns[br];

    int tid = threadIdx.x;
    int wave = tid >> 6, lane = tid & 63;
    int lrow = lane & 15, lgrp = lane >> 4;
    int e0 = blockIdx.x * 16;

    __shared__ unsigned short h1s[16 * 256];  // 8 KB

    // ---- GEMM1: (16 x 256) = dvs(16 x 160pad) @ W1; wave owns 64 cols
    int n0 = wave * 64;
    f32x4 acc1[4];
#pragma unroll
    for (int nt = 0; nt < 4; ++nt) {
        float bv = b1[n0 + nt * 16 + lrow];
        acc1[nt] = (f32x4){bv, bv, bv, bv};
    }
    const float4* dec4 = (const float4*)dec;
    int r = e0 + lrow;
#pragma unroll
    for (int kc = 0; kc < 5; ++kc) {
        short8 a;
        if (kc < 4) {
            float4 u0 = dec4[(size_t)r * 32 + kc * 8 + lgrp * 2];
            float4 u1 = dec4[(size_t)r * 32 + kc * 8 + lgrp * 2 + 1];
            a = pack8(u0, u1);
        } else {
            short8 z = (short8)0;
            if (lgrp == 0) {
                z[0] = (short)f2bf(A.ef[r * 2]);
                z[1] = (short)f2bf(A.ef[r * 2 + 1]);
                z[2] = (short)f2bf(A.gfeat[r * 4]);
                z[3] = (short)f2bf(A.gfeat[r * 4 + 1]);
                z[4] = (short)f2bf(A.gfeat[r * 4 + 2]);
                z[5] = (short)f2bf(A.gfeat[r * 4 + 3]);
            }
            a = z;
        }
#pragma unroll
        for (int nt = 0; nt < 4; ++nt) {
            short8 b = *(const short8*)(W1f + ((size_t)(kc * 16 + (n0 >> 4) + nt) * 64 + lane) * 8);
            acc1[nt] = __builtin_amdgcn_mfma_f32_16x16x32_bf16(a, b, acc1[nt], 0, 0, 0);
        }
    }
    // relu -> LDS (bf16, XOR-swizzled)
#pragma unroll
    for (int nt = 0; nt < 4; ++nt)
#pragma unroll
        for (int j = 0; j < 4; ++j) {
            int row = lgrp * 4 + j;
            int col = n0 + nt * 16 + lrow;
            h1s[row * 256 + (col ^ ((row & 7) << 3))] = f2bf(fmaxf(acc1[nt][j], 0.f));
        }
    __syncthreads();

    // ---- GEMM2 (folded): (16 x 128) = h1 @ W2A + b2A; wave owns 32 cols
    int c0 = wave * 32;
    f32x4 acc2[2];
#pragma unroll
    for (int nt = 0; nt < 2; ++nt) {
        float bv = b2A[c0 + nt * 16 + lrow];
        acc2[nt] = (f32x4){bv, bv, bv, bv};
    }
#pragma unroll
    for (int kc = 0; kc < 8; ++kc) {
        int kb = kc * 32 + lgrp * 8;
        short8 a2 = *(const short8*)(h1s + lrow * 256 + (kb ^ ((lrow & 7) << 3)));
#pragma unroll
        for (int nt = 0; nt < 2; ++nt) {
            short8 b = *(const short8*)(W2f + ((size_t)(kc * 8 + (c0 >> 4) + nt) * 64 + lane) * 8);
            acc2[nt] = __builtin_amdgcn_mfma_f32_16x16x32_bf16(a2, b, acc2[nt], 0, 0, 0);
        }
    }
    // Qb -> global; scatter-add into NS*
#pragma unroll
    for (int j = 0; j < 4; ++j) {
        int row = e0 + lgrp * 4 + j;
        int node = idx[row];
#pragma unroll
        for (int nt = 0; nt < 2; ++nt) {
            int col = c0 + nt * 16 + lrow;
            float v = acc2[nt][j];
            qbo[(size_t)row * 128 + col] = v;
            atomicAdd(ns + (size_t)node * 128 + col, v);
        }
    }
}

// ---------------------------------------------------------------------------
// Fused post (GEMM_p1 folded away): relu_in = NS*[idx]-Qb + ef@A1b + c1;
// a = relu(relu_in); o = a@A2+c2; out = m*o + (1-m)*old. No LDS, no barrier.
struct F2Args {
    const unsigned short* wpack[2];  // A2f @ 73728
    const float* a1[2];              // full A1 (130x128): rows 128/129 = ef part
    const float* c1[2];
    const float* c2[2];
    const float* qb[2];
    const float* ns[2];
    const int* idx[2];
    const float* ef;
    const float* emask;
    const float* oldst[2];
    float* outst[2];
};

__global__ __launch_bounds__(256, 6) void k_fused2(F2Args A) {
    int br = blockIdx.y;
    const unsigned short* A2f = A.wpack[br] + 73728;
    const float* A1e0 = A.a1[br] + 128 * 128;
    const float* A1e1 = A.a1[br] + 129 * 128;
    const float* c1 = A.c1[br];
    const float* c2 = A.c2[br];
    const float* qb = A.qb[br];
    const float* ns = A.ns[br];
    const int* idx = A.idx[br];
    const float* oldst = A.oldst[br];
    float* outst = A.outst[br];

    int tid = threadIdx.x;
    int wave = tid >> 6, lane = tid & 63;
    int lrow = lane & 15, lgrp = lane >> 4;
    int e0 = blockIdx.x * 16;
    int r = e0 + lrow;
    int node = idx[r];
    float ef0 = A.ef[r * 2], ef1 = A.ef[r * 2 + 1];

    const float4* ns4 = (const float4*)(ns + (size_t)node * 128);
    const float4* qb4 = (const float4*)(qb + (size_t)r * 128);

    int n0 = wave * 32;
    f32x4 acco[2];
#pragma unroll
    for (int nt = 0; nt < 2; ++nt) {
        float bv = c2[n0 + nt * 16 + lrow];
        acco[nt] = (f32x4){bv, bv, bv, bv};
    }
#pragma unroll
    for (int kc = 0; kc < 4; ++kc) {
        int k0 = kc * 32 + lgrp * 8;
        float4 u0 = ns4[k0 >> 2],       u1 = ns4[(k0 >> 2) + 1];
        float4 q0 = qb4[k0 >> 2],       q1 = qb4[(k0 >> 2) + 1];
        float4 w00 = *(const float4*)(A1e0 + k0), w01 = *(const float4*)(A1e0 + k0 + 4);
        float4 w10 = *(const float4*)(A1e1 + k0), w11 = *(const float4*)(A1e1 + k0 + 4);
        float4 cc0 = *(const float4*)(c1 + k0),   cc1 = *(const float4*)(c1 + k0 + 4);
        short8 a;
        a[0] = (short)f2bf(fmaxf(u0.x - q0.x + ef0 * w00.x + ef1 * w10.x + cc0.x, 0.f));
        a[1] = (short)f2bf(fmaxf(u0.y - q0.y + ef0 * w00.y + ef1 * w10.y + cc0.y, 0.f));
        a[2] = (short)f2bf(fmaxf(u0.z - q0.z + ef0 * w00.z + ef1 * w10.z + cc0.z, 0.f));
        a[3] = (short)f2bf(fmaxf(u0.w - q0.w + ef0 * w00.w + ef1 * w10.w + cc0.w, 0.f));
        a[4] = (short)f2bf(fmaxf(u1.x - q1.x + ef0 * w01.x + ef1 * w11.x + cc1.x, 0.f));
        a[5] = (short)f2bf(fmaxf(u1.y - q1.y + ef0 * w01.y + ef1 * w11.y + cc1.y, 0.f));
        a[6] = (short)f2bf(fmaxf(u1.z - q1.z + ef0 * w01.z + ef1 * w11.z + cc1.z, 0.f));
        a[7] = (short)f2bf(fmaxf(u1.w - q1.w + ef0 * w01.w + ef1 * w11.w + cc1.w, 0.f));
#pragma unroll
        for (int nt = 0; nt < 2; ++nt) {
            short8 b = *(const short8*)(A2f + ((size_t)(kc * 8 + (n0 >> 4) + nt) * 64 + lane) * 8);
            acco[nt] = __builtin_amdgcn_mfma_f32_16x16x32_bf16(a, b, acco[nt], 0, 0, 0);
        }
    }
#pragma unroll
    for (int j = 0; j < 4; ++j) {
        int row = e0 + lgrp * 4 + j;
        float m = A.emask[row];
#pragma unroll
        for (int nt = 0; nt < 2; ++nt) {
            int col = n0 + nt * 16 + lrow;
            float old = oldst[(size_t)row * 128 + col];
            outst[(size_t)row * 128 + col] = m * acco[nt][j] + (1.f - m) * old;
        }
    }
}

// ---------------------------------------------------------------------------
extern "C" void kernel_launch(void* const* d_in, const int* in_sizes, int n_in,
                              void* d_out, int out_size, void* d_ws, size_t ws_size,
                              hipStream_t stream) {
    const float* variable_state = (const float*)d_in[0];
    const float* function_state = (const float*)d_in[1];
    const float* dec_v          = (const float*)d_in[2];
    const float* dec_f          = (const float*)d_in[3];
    const float* ef             = (const float*)d_in[4];
    const float* meta           = (const float*)d_in[5];
    const int*   active         = (const int*)d_in[6];
    const float* vmask_t        = (const float*)d_in[8];
    const float* fmask_t        = (const float*)d_in[10];
    const float* bvm            = (const float*)d_in[11];
    const float* vM1w = (const float*)d_in[12]; const float* vM1b = (const float*)d_in[13];
    const float* vM2w = (const float*)d_in[14]; const float* vM2b = (const float*)d_in[15];
    const float* vA1w = (const float*)d_in[16]; const float* vA1b = (const float*)d_in[17];
    const float* vA2w = (const float*)d_in[18]; const float* vA2b = (const float*)d_in[19];
    const float* fM1w = (const float*)d_in[20]; const float* fM1b = (const float*)d_in[21];
    const float* fM2w = (const float*)d_in[22]; const float* fM2b = (const float*)d_in[23];
    const float* fA1w = (const float*)d_in[24]; const float* fA1b = (const float*)d_in[25];
    const float* fA2w = (const float*)d_in[26]; const float* fA2b = (const float*)d_in[27];

    float* out_vs = (float*)d_out;
    float* out_fs = (float*)d_out + (size_t)E_N * H_N;

    int*   var_idx = (int*)d_ws;                        // E
    int*   fun_idx = var_idx + E_N;                     // E
    float* emask   = (float*)(fun_idx + E_N);           // E
    float* gfeat   = emask + E_N;                       // 4E
    float* qv      = gfeat + (size_t)E_N * 4;           // 128E
    float* qf      = qv + (size_t)E_N * MEMAGG;         // 128E
    float* nsv     = qf + (size_t)E_N * MEMAGG;         // 128V
    float* nsf     = nsv + (size_t)V_N * MEMAGG;        // 128F
    float* b2A     = nsf + (size_t)F_N * MEMAGG;        // 256
    unsigned short* wpack = (unsigned short*)(b2A + 256);
    // per-branch pack: W1f 160*256=40960 | W2Af 256*128=32768 | A2f 128*128=16384
    const int PBR = 40960 + 32768 + 16384;              // 90112
    unsigned short* wpv = wpack;
    unsigned short* wpf = wpack + PBR;

    PrepArgs pp;
    pp.vmt = vmask_t; pp.fmt = fmask_t;
    pp.vidx = var_idx; pp.fidx = fun_idx;
    pp.bvm = bvm; pp.active = active; pp.meta = meta;
    pp.emask = emask; pp.gfeat = gfeat;
    pp.nszero = nsv;
    pp.vM2w = vM2w; pp.fM2w = fM2w;
    pp.vA1w = vA1w; pp.fA1w = fA1w;
    pp.vM2b = vM2b; pp.fM2b = fM2b;
    pp.w2afv = wpv + 40960;
    pp.w2aff = wpf + 40960;
    pp.b2A = b2A;
    pp.d[0] = {vM1w, wpv,          IN_DIM, MEMH, 160};
    pp.d[1] = {vA2w, wpv + 73728,  128,    H_N,  128};
    pp.d[2] = {fM1w, wpf,          IN_DIM, MEMH, 160};
    pp.d[3] = {fA2w, wpf + 73728,  128,    H_N,  128};
    k_prep<<<5121, 256, 0, stream>>>(pp);

    F1Args f1;
    f1.dec[0] = dec_v;  f1.dec[1] = dec_f;
    f1.ef = ef;         f1.gfeat = gfeat;
    f1.wpack[0] = wpv;  f1.wpack[1] = wpf;
    f1.b1[0] = vM1b;    f1.b1[1] = fM1b;
    f1.b2A[0] = b2A;    f1.b2A[1] = b2A + 128;
    f1.idx[0] = var_idx; f1.idx[1] = fun_idx;
    f1.qb[0] = qv;      f1.qb[1] = qf;
    f1.ns[0] = nsv;     f1.ns[1] = nsf;
    k_fused1<<<dim3(E_N / 16, 2), 256, 0, stream>>>(f1);

    F2Args f2;
    f2.wpack[0] = wpv;  f2.wpack[1] = wpf;
    f2.a1[0] = vA1w;    f2.a1[1] = fA1w;
    f2.c1[0] = vA1b;    f2.c1[1] = fA1b;
    f2.c2[0] = vA2b;    f2.c2[1] = fA2b;
    f2.qb[0] = qv;      f2.qb[1] = qf;
    f2.ns[0] = nsv;     f2.ns[1] = nsf;
    f2.idx[0] = var_idx; f2.idx[1] = fun_idx;
    f2.ef = ef;         f2.emask = emask;
    f2.oldst[0] = function_state;  f2.oldst[1] = variable_state;
    f2.outst[0] = out_fs;          f2.outst[1] = out_vs;
    k_fused2<<<dim3(E_N / 16, 2), 256, 0, stream>>>(f2);
}

// Round 13
// 55.008 us; speedup vs baseline: 1.1567x; 1.1567x over previous
//
#include <hip/hip_runtime.h>

#define E_N 8192
#define V_N 2048
#define F_N 2048
#define B_N 8
#define H_N 128
#define DEC_N 128
#define EDGE_N 2
#define META_N 4
#define IN_DIM 134
#define MEMH 256
#define MEMAGG 128
#define AGGH 128

typedef __attribute__((ext_vector_type(8))) short short8;
typedef __attribute__((ext_vector_type(4))) float f32x4;
typedef __attribute__((ext_vector_type(4))) unsigned short ushort4v;

__device__ inline unsigned short f2bf(float x) {
    unsigned u = __float_as_uint(x);
    unsigned r = (u + 0x7FFFu + ((u >> 16) & 1u)) >> 16;
    return (unsigned short)r;
}

__device__ inline short8 pack8(float4 u0, float4 u1) {
    short8 s;
    s[0] = (short)f2bf(u0.x); s[1] = (short)f2bf(u0.y);
    s[2] = (short)f2bf(u0.z); s[3] = (short)f2bf(u0.w);
    s[4] = (short)f2bf(u1.x); s[5] = (short)f2bf(u1.y);
    s[6] = (short)f2bf(u1.z); s[7] = (short)f2bf(u1.w);
    return s;
}

__device__ inline int probe4(float4 v, int c, int hit) {
    if (hit < 0) {
        if      (v.x != 0.f) hit = c;
        else if (v.y != 0.f) hit = c + 1;
        else if (v.z != 0.f) hit = c + 2;
        else if (v.w != 0.f) hit = c + 3;
    }
    return hit;
}

// ---------------------------------------------------------------------------
// k_prep, ONE launch. Latency-chain work (fold) FIRST so it hides under the
// scan stream; chunk-512 early-exit scans LAST (R8's proven variant):
//  [0,64)      FOLD W2A = W2 @ A1a -> direct MFMA B-frag bf16
//  64          b2A = b2 @ A1a (both branches)
//  [65,577)    zero NS* accumulators
//  [577,1025)  plain repack W1/A2 into MFMA B-frag bf16 (448 blocks)
//  [1025,5121) early-exit one-hot scans (1 row/wave, chunk-512)
struct RDesc { const float* src; unsigned short* dst; int K; int N; int Kp; };
struct PrepArgs {
    const float* vmt; const float* fmt;
    int* vidx; int* fidx;
    const float* bvm; const int* active; const float* meta;
    float* emask; float* gfeat;
    float* nszero;
    const float* vM2w; const float* fM2w;
    const float* vA1w; const float* fA1w;
    const float* vM2b; const float* fM2b;
    unsigned short* w2afv;   // wpv + 40960 (256x128 frag)
    unsigned short* w2aff;   // wpf + 40960
    float* b2A;              // [0..127] var, [128..255] fun
    RDesc d[4];
};
__constant__ const int RP_CUM[5] = {0, 160, 224, 384, 448};

__global__ __launch_bounds__(256) void k_prep(PrepArgs P) {
    int bid = blockIdx.x, tid = threadIdx.x;
    if (bid >= 1025) {                      // early-exit scan, 4096 blocks
        int row = (bid - 1025) * 4 + (tid >> 6);   // one row per wave
        int lane = tid & 63;
        bool isVar = row < E_N;
        const float* m = isVar ? P.vmt : P.fmt;
        int* out = isVar ? P.vidx : P.fidx;
        int e = isVar ? row : row - E_N;
        const float4* rp = (const float4*)(m + (size_t)e * V_N);

        int hit = -1;
        float4 a0 = rp[lane], a1 = rp[64 + lane];
        hit = probe4(a0, lane * 4, hit);
        hit = probe4(a1, (64 + lane) * 4, hit);
        unsigned long long bm = __ballot(hit >= 0);
        for (int base = 128; base < 512 && !bm; base += 128) {
            float4 v0 = rp[base + lane], v1 = rp[base + 64 + lane];
            hit = probe4(v0, (base + lane) * 4, hit);
            hit = probe4(v1, (base + 64 + lane) * 4, hit);
            bm = __ballot(hit >= 0);
        }
        int pos = __shfl(hit, __ffsll((long long)bm) - 1);
        if (lane == 0) {
            out[e] = pos;
            if (isVar) {
                const float4* bv = (const float4*)(P.bvm + pos * 8);
                float4 x0 = bv[0], x1 = bv[1];
                float s = x0.y + 2.f * x0.z + 3.f * x0.w +
                          4.f * x1.x + 5.f * x1.y + 6.f * x1.z + 7.f * x1.w;
                int b = (int)(s + 0.5f);
                P.emask[e] = (float)P.active[b];
                ((float4*)P.gfeat)[e] = ((const float4*)P.meta)[b];
            }
        }
        return;
    }
    if (bid < 64) {                         // W2A fold -> direct frag write
        int br = bid >> 5;
        const float* W2 = br ? P.fM2w : P.vM2w;
        const float* A1 = br ? P.fA1w : P.vA1w;
        unsigned short* dst = br ? P.w2aff : P.w2afv;
        int c  = tid & 127;
        int k0 = (bid & 31) * 8 + (tid >> 7) * 4;
        float acc0 = 0.f, acc1 = 0.f, acc2 = 0.f, acc3 = 0.f;
#pragma unroll 8
        for (int j = 0; j < 128; ++j) {
            float a1 = A1[(size_t)j * 128 + c];
            acc0 += W2[(size_t)(k0 + 0) * 128 + j] * a1;
            acc1 += W2[(size_t)(k0 + 1) * 128 + j] * a1;
            acc2 += W2[(size_t)(k0 + 2) * 128 + j] * a1;
            acc3 += W2[(size_t)(k0 + 3) * 128 + j] * a1;
        }
        int f    = (k0 >> 5) * 8 + (c >> 4);
        int lane = ((k0 >> 3) & 3) * 16 + (c & 15);
        ushort4v o;
        o[0] = f2bf(acc0); o[1] = f2bf(acc1); o[2] = f2bf(acc2); o[3] = f2bf(acc3);
        *(ushort4v*)(dst + ((size_t)(f * 64 + lane) * 8 + (k0 & 7))) = o;
        return;
    }
    if (bid == 64) {                        // b2A fold
        int n = tid & 127;
        const float* b2 = (tid < 128) ? P.vM2b : P.fM2b;
        const float* A1 = (tid < 128) ? P.vA1w : P.fA1w;
        float acc = 0.f;
#pragma unroll 8
        for (int j = 0; j < 128; ++j) acc += b2[j] * A1[(size_t)j * 128 + n];
        P.b2A[tid] = acc;
        return;
    }
    if (bid < 577) {                        // zero node sums: 512 blocks
        int gid = (bid - 65) * 256 + tid;
        ((float4*)P.nszero)[gid] = (float4){0.f, 0.f, 0.f, 0.f};
        return;
    }
    int rb = bid - 577;                     // plain repack: 448 blocks
    int mi = 0;
#pragma unroll
    for (int t = 1; t < 4; ++t) if (rb >= RP_CUM[t]) mi = t;
    RDesc d = P.d[mi];
    int i = (rb - RP_CUM[mi]) * 256 + tid;
    if (i >= d.Kp * d.N) return;
    int elem = i & 7;
    int lane = (i >> 3) & 63;
    int f    = i >> 9;
    int c16n = d.N >> 4;
    int c16 = f % c16n, kc = f / c16n;
    int k = kc * 32 + (lane >> 4) * 8 + elem;
    int c = c16 * 16 + (lane & 15);
    float v = (k < d.K) ? d.src[(size_t)k * d.N + c] : 0.f;
    d.dst[i] = f2bf(v);
}

// ---------------------------------------------------------------------------
// Fused MLP1 + folded-GEMM2: h1 = relu(dvs@W1+b1); Qb = h1@W2A + b2A
// -> global + atomic scatter into NS*. 16 edges/block (4 waves), grid 512x2.
struct F1Args {
    const float* dec[2];
    const float* ef;
    const float* gfeat;
    const unsigned short* wpack[2];  // W1f@0 (160x256), W2Af@40960 (256x128)
    const float* b1[2];
    const float* b2A[2];
    const int* idx[2];
    float* qb[2];
    float* ns[2];
};

__global__ __launch_bounds__(256, 6) void k_fused1(F1Args A) {
    int br = blockIdx.y;
    const float* dec = A.dec[br];
    const unsigned short* W1f = A.wpack[br];
    const unsigned short* W2f = A.wpack[br] + 160 * 256;
    const float* b1 = A.b1[br];
    const float* b2A = A.b2A[br];
    const int* idx = A.idx[br];
    float* qbo = A.qb[br];
    float* ns  = A.ns[br];

    int tid = threadIdx.x;
    int wave = tid >> 6, lane = tid & 63;
    int lrow = lane & 15, lgrp = lane >> 4;
    int e0 = blockIdx.x * 16;

    __shared__ unsigned short h1s[16 * 256];  // 8 KB

    // ---- GEMM1: (16 x 256) = dvs(16 x 160pad) @ W1; wave owns 64 cols
    int n0 = wave * 64;
    f32x4 acc1[4];
#pragma unroll
    for (int nt = 0; nt < 4; ++nt) {
        float bv = b1[n0 + nt * 16 + lrow];
        acc1[nt] = (f32x4){bv, bv, bv, bv};
    }
    const float4* dec4 = (const float4*)dec;
    int r = e0 + lrow;
#pragma unroll
    for (int kc = 0; kc < 5; ++kc) {
        short8 a;
        if (kc < 4) {
            float4 u0 = dec4[(size_t)r * 32 + kc * 8 + lgrp * 2];
            float4 u1 = dec4[(size_t)r * 32 + kc * 8 + lgrp * 2 + 1];
            a = pack8(u0, u1);
        } else {
            short8 z = (short8)0;
            if (lgrp == 0) {
                z[0] = (short)f2bf(A.ef[r * 2]);
                z[1] = (short)f2bf(A.ef[r * 2 + 1]);
                z[2] = (short)f2bf(A.gfeat[r * 4]);
                z[3] = (short)f2bf(A.gfeat[r * 4 + 1]);
                z[4] = (short)f2bf(A.gfeat[r * 4 + 2]);
                z[5] = (short)f2bf(A.gfeat[r * 4 + 3]);
            }
            a = z;
        }
#pragma unroll
        for (int nt = 0; nt < 4; ++nt) {
            short8 b = *(const short8*)(W1f + ((size_t)(kc * 16 + (n0 >> 4) + nt) * 64 + lane) * 8);
            acc1[nt] = __builtin_amdgcn_mfma_f32_16x16x32_bf16(a, b, acc1[nt], 0, 0, 0);
        }
    }
    // relu -> LDS (bf16, XOR-swizzled)
#pragma unroll
    for (int nt = 0; nt < 4; ++nt)
#pragma unroll
        for (int j = 0; j < 4; ++j) {
            int row = lgrp * 4 + j;
            int col = n0 + nt * 16 + lrow;
            h1s[row * 256 + (col ^ ((row & 7) << 3))] = f2bf(fmaxf(acc1[nt][j], 0.f));
        }
    __syncthreads();

    // ---- GEMM2 (folded): (16 x 128) = h1 @ W2A + b2A; wave owns 32 cols
    int c0 = wave * 32;
    f32x4 acc2[2];
#pragma unroll
    for (int nt = 0; nt < 2; ++nt) {
        float bv = b2A[c0 + nt * 16 + lrow];
        acc2[nt] = (f32x4){bv, bv, bv, bv};
    }
#pragma unroll
    for (int kc = 0; kc < 8; ++kc) {
        int kb = kc * 32 + lgrp * 8;
        short8 a2 = *(const short8*)(h1s + lrow * 256 + (kb ^ ((lrow & 7) << 3)));
#pragma unroll
        for (int nt = 0; nt < 2; ++nt) {
            short8 b = *(const short8*)(W2f + ((size_t)(kc * 8 + (c0 >> 4) + nt) * 64 + lane) * 8);
            acc2[nt] = __builtin_amdgcn_mfma_f32_16x16x32_bf16(a2, b, acc2[nt], 0, 0, 0);
        }
    }
    // Qb -> global; scatter-add into NS*
#pragma unroll
    for (int j = 0; j < 4; ++j) {
        int row = e0 + lgrp * 4 + j;
        int node = idx[row];
#pragma unroll
        for (int nt = 0; nt < 2; ++nt) {
            int col = c0 + nt * 16 + lrow;
            float v = acc2[nt][j];
            qbo[(size_t)row * 128 + col] = v;
            atomicAdd(ns + (size_t)node * 128 + col, v);
        }
    }
}

// ---------------------------------------------------------------------------
// Fused post (GEMM_p1 folded away): relu_in = NS*[idx]-Qb + ef@A1b + c1;
// a = relu(relu_in); o = a@A2+c2; out = m*o + (1-m)*old. No LDS, no barrier.
struct F2Args {
    const unsigned short* wpack[2];  // A2f @ 73728
    const float* a1[2];              // full A1 (130x128): rows 128/129 = ef part
    const float* c1[2];
    const float* c2[2];
    const float* qb[2];
    const float* ns[2];
    const int* idx[2];
    const float* ef;
    const float* emask;
    const float* oldst[2];
    float* outst[2];
};

__global__ __launch_bounds__(256, 6) void k_fused2(F2Args A) {
    int br = blockIdx.y;
    const unsigned short* A2f = A.wpack[br] + 73728;
    const float* A1e0 = A.a1[br] + 128 * 128;
    const float* A1e1 = A.a1[br] + 129 * 128;
    const float* c1 = A.c1[br];
    const float* c2 = A.c2[br];
    const float* qb = A.qb[br];
    const float* ns = A.ns[br];
    const int* idx = A.idx[br];
    const float* oldst = A.oldst[br];
    float* outst = A.outst[br];

    int tid = threadIdx.x;
    int wave = tid >> 6, lane = tid & 63;
    int lrow = lane & 15, lgrp = lane >> 4;
    int e0 = blockIdx.x * 16;
    int r = e0 + lrow;
    int node = idx[r];
    float ef0 = A.ef[r * 2], ef1 = A.ef[r * 2 + 1];

    const float4* ns4 = (const float4*)(ns + (size_t)node * 128);
    const float4* qb4 = (const float4*)(qb + (size_t)r * 128);

    int n0 = wave * 32;
    f32x4 acco[2];
#pragma unroll
    for (int nt = 0; nt < 2; ++nt) {
        float bv = c2[n0 + nt * 16 + lrow];
        acco[nt] = (f32x4){bv, bv, bv, bv};
    }
#pragma unroll
    for (int kc = 0; kc < 4; ++kc) {
        int k0 = kc * 32 + lgrp * 8;
        float4 u0 = ns4[k0 >> 2],       u1 = ns4[(k0 >> 2) + 1];
        float4 q0 = qb4[k0 >> 2],       q1 = qb4[(k0 >> 2) + 1];
        float4 w00 = *(const float4*)(A1e0 + k0), w01 = *(const float4*)(A1e0 + k0 + 4);
        float4 w10 = *(const float4*)(A1e1 + k0), w11 = *(const float4*)(A1e1 + k0 + 4);
        float4 cc0 = *(const float4*)(c1 + k0),   cc1 = *(const float4*)(c1 + k0 + 4);
        short8 a;
        a[0] = (short)f2bf(fmaxf(u0.x - q0.x + ef0 * w00.x + ef1 * w10.x + cc0.x, 0.f));
        a[1] = (short)f2bf(fmaxf(u0.y - q0.y + ef0 * w00.y + ef1 * w10.y + cc0.y, 0.f));
        a[2] = (short)f2bf(fmaxf(u0.z - q0.z + ef0 * w00.z + ef1 * w10.z + cc0.z, 0.f));
        a[3] = (short)f2bf(fmaxf(u0.w - q0.w + ef0 * w00.w + ef1 * w10.w + cc0.w, 0.f));
        a[4] = (short)f2bf(fmaxf(u1.x - q1.x + ef0 * w01.x + ef1 * w11.x + cc1.x, 0.f));
        a[5] = (short)f2bf(fmaxf(u1.y - q1.y + ef0 * w01.y + ef1 * w11.y + cc1.y, 0.f));
        a[6] = (short)f2bf(fmaxf(u1.z - q1.z + ef0 * w01.z + ef1 * w11.z + cc1.z, 0.f));
        a[7] = (short)f2bf(fmaxf(u1.w - q1.w + ef0 * w01.w + ef1 * w11.w + cc1.w, 0.f));
#pragma unroll
        for (int nt = 0; nt < 2; ++nt) {
            short8 b = *(const short8*)(A2f + ((size_t)(kc * 8 + (n0 >> 4) + nt) * 64 + lane) * 8);
            acco[nt] = __builtin_amdgcn_mfma_f32_16x16x32_bf16(a, b, acco[nt], 0, 0, 0);
        }
    }
#pragma unroll
    for (int j = 0; j < 4; ++j) {
        int row = e0 + lgrp * 4 + j;
        float m = A.emask[row];
#pragma unroll
        for (int nt = 0; nt < 2; ++nt) {
            int col = n0 + nt * 16 + lrow;
            float old = oldst[(size_t)row * 128 + col];
            outst[(size_t)row * 128 + col] = m * acco[nt][j] + (1.f - m) * old;
        }
    }
}

// ---------------------------------------------------------------------------
extern "C" void kernel_launch(void* const* d_in, const int* in_sizes, int n_in,
                              void* d_out, int out_size, void* d_ws, size_t ws_size,
                              hipStream_t stream) {
    const float* variable_state = (const float*)d_in[0];
    const float* function_state = (const float*)d_in[1];
    const float* dec_v          = (const float*)d_in[2];
    const float* dec_f          = (const float*)d_in[3];
    const float* ef             = (const float*)d_in[4];
    const float* meta           = (const float*)d_in[5];
    const int*   active         = (const int*)d_in[6];
    const float* vmask_t        = (const float*)d_in[8];
    const float* fmask_t        = (const float*)d_in[10];
    const float* bvm            = (const float*)d_in[11];
    const float* vM1w = (const float*)d_in[12]; const float* vM1b = (const float*)d_in[13];
    const float* vM2w = (const float*)d_in[14]; const float* vM2b = (const float*)d_in[15];
    const float* vA1w = (const float*)d_in[16]; const float* vA1b = (const float*)d_in[17];
    const float* vA2w = (const float*)d_in[18]; const float* vA2b = (const float*)d_in[19];
    const float* fM1w = (const float*)d_in[20]; const float* fM1b = (const float*)d_in[21];
    const float* fM2w = (const float*)d_in[22]; const float* fM2b = (const float*)d_in[23];
    const float* fA1w = (const float*)d_in[24]; const float* fA1b = (const float*)d_in[25];
    const float* fA2w = (const float*)d_in[26]; const float* fA2b = (const float*)d_in[27];

    float* out_vs = (float*)d_out;
    float* out_fs = (float*)d_out + (size_t)E_N * H_N;

    int*   var_idx = (int*)d_ws;                        // E
    int*   fun_idx = var_idx + E_N;                     // E
    float* emask   = (float*)(fun_idx + E_N);           // E
    float* gfeat   = emask + E_N;                       // 4E
    float* qv      = gfeat + (size_t)E_N * 4;           // 128E
    float* qf      = qv + (size_t)E_N * MEMAGG;         // 128E
    float* nsv     = qf + (size_t)E_N * MEMAGG;         // 128V
    float* nsf     = nsv + (size_t)V_N * MEMAGG;        // 128F
    float* b2A     = nsf + (size_t)F_N * MEMAGG;        // 256
    unsigned short* wpack = (unsigned short*)(b2A + 256);
    // per-branch pack: W1f 160*256=40960 | W2Af 256*128=32768 | A2f 128*128=16384
    const int PBR = 40960 + 32768 + 16384;              // 90112
    unsigned short* wpv = wpack;
    unsigned short* wpf = wpack + PBR;

    PrepArgs pp;
    pp.vmt = vmask_t; pp.fmt = fmask_t;
    pp.vidx = var_idx; pp.fidx = fun_idx;
    pp.bvm = bvm; pp.active = active; pp.meta = meta;
    pp.emask = emask; pp.gfeat = gfeat;
    pp.nszero = nsv;
    pp.vM2w = vM2w; pp.fM2w = fM2w;
    pp.vA1w = vA1w; pp.fA1w = fA1w;
    pp.vM2b = vM2b; pp.fM2b = fM2b;
    pp.w2afv = wpv + 40960;
    pp.w2aff = wpf + 40960;
    pp.b2A = b2A;
    pp.d[0] = {vM1w, wpv,          IN_DIM, MEMH, 160};
    pp.d[1] = {vA2w, wpv + 73728,  128,    H_N,  128};
    pp.d[2] = {fM1w, wpf,          IN_DIM, MEMH, 160};
    pp.d[3] = {fA2w, wpf + 73728,  128,    H_N,  128};
    k_prep<<<5121, 256, 0, stream>>>(pp);

    F1Args f1;
    f1.dec[0] = dec_v;  f1.dec[1] = dec_f;
    f1.ef = ef;         f1.gfeat = gfeat;
    f1.wpack[0] = wpv;  f1.wpack[1] = wpf;
    f1.b1[0] = vM1b;    f1.b1[1] = fM1b;
    f1.b2A[0] = b2A;    f1.b2A[1] = b2A + 128;
    f1.idx[0] = var_idx; f1.idx[1] = fun_idx;
    f1.qb[0] = qv;      f1.qb[1] = qf;
    f1.ns[0] = nsv;     f1.ns[1] = nsf;
    k_fused1<<<dim3(E_N / 16, 2), 256, 0, stream>>>(f1);

    F2Args f2;
    f2.wpack[0] = wpv;  f2.wpack[1] = wpf;
    f2.a1[0] = vA1w;    f2.a1[1] = fA1w;
    f2.c1[0] = vA1b;    f2.c1[1] = fA1b;
    f2.c2[0] = vA2b;    f2.c2[1] = fA2b;
    f2.qb[0] = qv;      f2.qb[1] = qf;
    f2.ns[0] = nsv;     f2.ns[1] = nsf;
    f2.idx[0] = var_idx; f2.idx[1] = fun_idx;
    f2.ef = ef;         f2.emask = emask;
    f2.oldst[0] = function_state;  f2.oldst[1] = variable_state;
    f2.outst[0] = out_fs;          f2.outst[1] = out_vs;
    k_fused2<<<dim3(E_N / 16, 2), 256, 0, stream>>>(f2);
}